// Round 2
// baseline (111.307 us; speedup 1.0000x reference)
//
#include <hip/hip_runtime.h>

typedef unsigned long long u64;

#define CC 32
#define NN 512
#define TT 12
#define NBLK 256     // one block per (batch, channel)
#define NTHR 512     // one n-element per thread

__device__ __forceinline__ float eluf(float x){ return x>0.f ? x : (expf(x)-1.f); }
__device__ __forceinline__ float sigmf(float x){
  if (x>=0.f) return 1.f/(1.f+expf(-x));
  float e=expf(x); return e/(1.f+e);
}
__device__ __forceinline__ u64 pack_slot(unsigned tag, float v){
  return ((u64)tag<<32) | (u64)__float_as_uint(v);
}
__device__ __forceinline__ u64 ld_slot(u64* p){
  return __hip_atomic_load(p, __ATOMIC_RELAXED, __HIP_MEMORY_SCOPE_AGENT);
}
__device__ __forceinline__ void st_slot(u64* p, u64 v){
  __hip_atomic_store(p, v, __ATOMIC_RELAXED, __HIP_MEMORY_SCOPE_AGENT);
}

__global__ __launch_bounds__(NTHR, 1)
void glstm_fused(const float* __restrict__ xg,     // (B,C,N,T)
                 const float* __restrict__ cellg,  // (B,C,N)
                 const float* __restrict__ w1g,    // (T,8,C,C)
                 const float* __restrict__ w2g,    // (T,8,C,C)
                 const float* __restrict__ biasg,  // (4,C,N,T)
                 float* __restrict__ outg,         // (B,C,N,T) ++ (B,C,N)
                 u64* slots)
{
  __shared__ float preS[2][4];       // double-buffered gate broadcast
  __shared__ float xpart[TT][8];     // prologue xsum wave-partials

  const int blk  = blockIdx.x;
  const int b    = blk & 7;          // batch groups XCD-local (blk%8 -> XCD)
  const int ch   = blk >> 3;
  const int row  = b*CC + ch;        // logical (b,c) row for memory indexing
  const int tid  = threadIdx.x;
  const int lane = tid & 63;
  const int wv   = tid >> 6;         // 0..7
  const int i0   = lane & 31;
  const int jbase = (lane >> 5) << 4;   // 0 (lo half) / 16 (hi half)
  const int pbase = (lane >> 5) << 2;   // partial slots 0-3 / 4-7

  u64* csum_part = slots;                 // [2][8][NBLK] tagged wave-partials
  u64* xsum_slot = slots + 2*8*NBLK;      // [TT][NBLK]   tagged, tag=1

  // ---- per-thread state: c element + 48 bias regs ----
  const int n0 = tid;
  float c = cellg[row*NN + n0];

  float bias0[TT], bias1[TT], bias2[TT], bias3[TT];
  #pragma unroll
  for (int k=0;k<4;k++){
    const float4* p = (const float4*)(biasg + ((k*CC+ch)*NN + n0)*TT);
    float4 v0=p[0], v1=p[1], v2=p[2];
    float* dst = (k==0)?bias0:(k==1)?bias1:(k==2)?bias2:bias3;
    dst[0]=v0.x; dst[1]=v0.y; dst[2]=v0.z;  dst[3]=v0.w;
    dst[4]=v1.x; dst[5]=v1.y; dst[6]=v1.z;  dst[7]=v1.w;
    dst[8]=v2.x; dst[9]=v2.y; dst[10]=v2.z; dst[11]=v2.w;
  }

  // ---- phase 0: xsum per t + csum(state0), publish wave-partials ----
  float xs[TT];
  {
    const float4* p = (const float4*)(xg + (row*NN + n0)*TT);
    float4 v0=p[0], v1=p[1], v2=p[2];
    xs[0]=v0.x; xs[1]=v0.y; xs[2]=v0.z;  xs[3]=v0.w;
    xs[4]=v1.x; xs[5]=v1.y; xs[6]=v1.z;  xs[7]=v1.w;
    xs[8]=v2.x; xs[9]=v2.y; xs[10]=v2.z; xs[11]=v2.w;
  }
  float cp = c;
  #pragma unroll
  for (int off=32; off>=1; off>>=1){
    #pragma unroll
    for (int t=0;t<TT;t++) xs[t] += __shfl_xor(xs[t], off, 64);
    cp += __shfl_xor(cp, off, 64);
  }
  if (lane==0){
    #pragma unroll
    for (int t=0;t<TT;t++) xpart[t][wv] = xs[t];
    // csum state0: parity 0, tag 1, wave-partial wv
    st_slot(&csum_part[wv*NBLK + row], pack_slot(1u, cp));
  }
  __syncthreads();
  if (tid < TT){
    float v = 0.f;
    #pragma unroll
    for (int w8=0; w8<8; w8++) v += xpart[tid][w8];
    st_slot(&xsum_slot[tid*NBLK + row], pack_slot(1u, v));
  }

  // ---- precompute x-head outputs ovx[s] (waves 0-3, head m=wv) ----
  float ovx[TT];
  if (wv < 4){
    const int m = wv;
    #pragma unroll
    for (int s=0;s<TT;s++){
      u64* sl = &xsum_slot[s*NBLK + b*CC + i0];
      u64 v = ld_slot(sl);
      int guard = 0;
      while ((unsigned)(v>>32) != 1u){
        __builtin_amdgcn_s_sleep(1);
        v = ld_slot(sl);
        if (++guard > 1000000) break;
      }
      float zs = __uint_as_float((unsigned)v);
      const float* w1m = w1g + (s*8+m)*CC*CC + i0;
      float part = 0.f;
      #pragma unroll
      for (int jj=0;jj<16;jj++){
        int j = jbase + jj;
        float a = __shfl(zs, j, 32);
        part = fmaf(a, w1m[j*CC], part);
      }
      float s1 = part + __shfl_xor(part, 32, 64);
      float h1 = eluf(eluf(s1));
      float pp = h1 * w2g[((s*8+m)*CC + i0)*CC + ch];
      #pragma unroll
      for (int off=16; off>=1; off>>=1) pp += __shfl_xor(pp, off, 32);
      ovx[s] = eluf(eluf(eluf(512.f*pp)));
    }
  }

  // ---- 12 sequential steps (fully unrolled: static reg-array indexing) ----
  float hm[TT];
  #pragma unroll
  for (int s=0;s<TT;s++){
    if (wv < 4){
      const int m = wv + 4;                      // c-head
      const unsigned want = (unsigned)(s+1);
      u64* base = &csum_part[(((s&1)<<3) + pbase)*NBLK + b*CC + i0];
      u64 v0,v1,v2,v3; int guard = 0;
      for(;;){
        v0 = ld_slot(base);
        v1 = ld_slot(base +   NBLK);
        v2 = ld_slot(base + 2*NBLK);
        v3 = ld_slot(base + 3*NBLK);
        if ((unsigned)(v0>>32)==want && (unsigned)(v1>>32)==want &&
            (unsigned)(v2>>32)==want && (unsigned)(v3>>32)==want) break;
        __builtin_amdgcn_s_sleep(1);
        if (++guard > 1000000) break;
      }
      float zh = __uint_as_float((unsigned)v0) + __uint_as_float((unsigned)v1)
               + __uint_as_float((unsigned)v2) + __uint_as_float((unsigned)v3);
      float zs = zh + __shfl_xor(zh, 32, 64);    // full csum[b][i0] on all lanes
      const float* w1m = w1g + (s*8+m)*CC*CC + i0;
      float part = 0.f;
      #pragma unroll
      for (int jj=0;jj<16;jj++){
        int j = jbase + jj;
        float a = __shfl(zs, j, 32);
        part = fmaf(a, w1m[j*CC], part);
      }
      float s1 = part + __shfl_xor(part, 32, 64);
      float h1 = eluf(eluf(s1));
      float pp = h1 * w2g[((s*8+m)*CC + i0)*CC + ch];
      #pragma unroll
      for (int off=16; off>=1; off>>=1) pp += __shfl_xor(pp, off, 32);
      float ovc = eluf(eluf(eluf(512.f*pp)));
      if (lane==0) preS[s&1][wv] = ovx[s] + ovc;
    }
    __syncthreads();
    const float g0 = preS[s&1][0], g1 = preS[s&1][1];
    const float g2 = preS[s&1][2], g3 = preS[s&1][3];

    float ig = sigmf(g0 + bias0[s]);
    float fg = sigmf(g1 + bias1[s]);
    float ct = tanhf(g3 + bias3[s]);
    c = fg*c + ig*ct;

    if (s < TT-1){
      float csp = c;
      #pragma unroll
      for (int off=32; off>=1; off>>=1) csp += __shfl_xor(csp, off, 64);
      if (lane==0)
        st_slot(&csum_part[((((s+1)&1)<<3) + wv)*NBLK + row],
                pack_slot((unsigned)(s+2), csp));
    }
    hm[s] = sigmf(g2 + bias2[s]) * tanhf(c);
  }

  // ---- coalesced epilogue ----
  float4* op = (float4*)(outg + (row*NN + n0)*TT);
  op[0] = make_float4(hm[0], hm[1], hm[2],  hm[3]);
  op[1] = make_float4(hm[4], hm[5], hm[6],  hm[7]);
  op[2] = make_float4(hm[8], hm[9], hm[10], hm[11]);
  outg[NBLK*NN*TT + row*NN + n0] = c;
}

extern "C" void kernel_launch(void* const* d_in, const int* in_sizes, int n_in,
                              void* d_out, int out_size, void* d_ws, size_t ws_size,
                              hipStream_t stream)
{
  (void)in_sizes; (void)n_in; (void)out_size; (void)ws_size;
  // setup_inputs order: input, cell, adj, w1, a1, w2, a2, bias
  const float* xg    = (const float*)d_in[0];
  const float* cellg = (const float*)d_in[1];
  const float* w1g   = (const float*)d_in[3];
  const float* w2g   = (const float*)d_in[5];
  const float* biasg = (const float*)d_in[7];
  float* outg = (float*)d_out;
  u64* slots = (u64*)d_ws;

  // reset sync tags every launch (ws is not re-poisoned between replays)
  hipMemsetAsync(d_ws, 0, (size_t)(2*8*NBLK + TT*NBLK)*sizeof(u64), stream);
  glstm_fused<<<dim3(NBLK), dim3(NTHR), 0, stream>>>(xg, cellg, w1g, w2g, biasg, outg, slots);
}

// Round 3
// 89.741 us; speedup vs baseline: 1.2403x; 1.2403x over previous
//
#include <hip/hip_runtime.h>

typedef unsigned long long u64;

#define CC 32
#define NN 512
#define TT 12
#define NBLK 256     // one block per (batch, channel)
#define NTHR 512     // one n-element per thread

__device__ __forceinline__ float eluf(float x){ return x>0.f ? x : (__expf(x)-1.f); }
__device__ __forceinline__ float elu3f(float x){ return eluf(eluf(eluf(x))); }
__device__ __forceinline__ float sigmf(float x){
  if (x>=0.f) return 1.f/(1.f+__expf(-x));
  float e=__expf(x); return e/(1.f+e);
}
__device__ __forceinline__ float tanhff(float x){
  return 1.f - 2.f/(__expf(2.f*x)+1.f);   // safe at +/-inf of exp
}
__device__ __forceinline__ u64 pack_slot(unsigned tag, float v){
  return ((u64)tag<<32) | (u64)__float_as_uint(v);
}
__device__ __forceinline__ u64 ld_slot(u64* p){
  return __hip_atomic_load(p, __ATOMIC_RELAXED, __HIP_MEMORY_SCOPE_AGENT);
}
__device__ __forceinline__ void st_slot(u64* p, u64 v){
  __hip_atomic_store(p, v, __ATOMIC_RELAXED, __HIP_MEMORY_SCOPE_AGENT);
}
__device__ __forceinline__ float poll_slot(u64* p, unsigned want){
  u64 v = ld_slot(p);
  int guard = 0;
  while ((unsigned)(v>>32) != want){
    __builtin_amdgcn_s_sleep(1);
    v = ld_slot(p);
    if (++guard > 1000000) break;   // terminates instead of hanging
  }
  return __uint_as_float((unsigned)v);
}

// One GAT head output for output-channel ch: zs = input rowsum vector (lane i0
// holds zs[i0], duplicated across lane halves). Returns elu^3(N * (elu^2(w1^T zs)) . w2[:,ch])
// on all 64 lanes. w1r[jj] = w1[jbase+jj][i0]; w2r = w2[i0][ch].
__device__ __forceinline__ float head_out(float zs, const float* w1r, float w2r, int jbase){
  float pa = 0.f, pb = 0.f;
  #pragma unroll
  for (int jj=0; jj<8; jj++){
    pa = fmaf(__shfl(zs, jbase+jj,   32), w1r[jj],   pa);
    pb = fmaf(__shfl(zs, jbase+8+jj, 32), w1r[8+jj], pb);
  }
  float part = pa + pb;
  float s1 = part + __shfl_xor(part, 32, 64);     // full 32-dot on both halves
  float h1 = eluf(eluf(s1));
  float pp = h1 * w2r;
  #pragma unroll
  for (int off=16; off>=1; off>>=1) pp += __shfl_xor(pp, off, 32);
  return elu3f(512.f*pp);
}

__global__ __launch_bounds__(NTHR, 1)
void glstm_fused(const float* __restrict__ xg,     // (B,C,N,T)
                 const float* __restrict__ cellg,  // (B,C,N)
                 const float* __restrict__ w1g,    // (T,8,C,C)
                 const float* __restrict__ w2g,    // (T,8,C,C)
                 const float* __restrict__ biasg,  // (4,C,N,T)
                 float* __restrict__ outg,         // (B,C,N,T) ++ (B,C,N)
                 u64* slots)
{
  __shared__ float xpart[TT][8];
  __shared__ float cpartS[8];
  __shared__ float ovxL[TT][4];      // x-head outputs, filled 1 step ahead
  __shared__ float preS[2][4];       // gate pre-activations, parity-buffered
  __shared__ float redS[8];

  const int blk  = blockIdx.x;
  const int b    = blk & 7;          // batch groups XCD-local under round-robin
  const int ch   = blk >> 3;
  const int row  = b*CC + ch;
  const int tid  = threadIdx.x;
  const int lane = tid & 63;
  const int wv   = tid >> 6;         // 0..7
  const int i0   = lane & 31;
  const int jbase = (lane >> 5) << 4;

  u64* cs_slot = slots;              // [2][NBLK] single tagged slot per row/parity
  u64* xs_slot = slots + 2*NBLK;     // [TT][NBLK] tag=1 when ready

  // ---- per-thread state ----
  const int n0 = tid;
  float c = cellg[row*NN + n0];

  float bias0[TT], bias1[TT], bias2[TT], bias3[TT];
  #pragma unroll
  for (int k=0;k<4;k++){
    const float4* p = (const float4*)(biasg + ((k*CC+ch)*NN + n0)*TT);
    float4 v0=p[0], v1=p[1], v2=p[2];
    float* dst = (k==0)?bias0:(k==1)?bias1:(k==2)?bias2:bias3;
    dst[0]=v0.x; dst[1]=v0.y; dst[2]=v0.z;  dst[3]=v0.w;
    dst[4]=v1.x; dst[5]=v1.y; dst[6]=v1.z;  dst[7]=v1.w;
    dst[8]=v2.x; dst[9]=v2.y; dst[10]=v2.z; dst[11]=v2.w;
  }

  // ---- prologue: xsum per t + csum(state0) ----
  float xs[TT];
  {
    const float4* p = (const float4*)(xg + (row*NN + n0)*TT);
    float4 v0=p[0], v1=p[1], v2=p[2];
    xs[0]=v0.x; xs[1]=v0.y; xs[2]=v0.z;  xs[3]=v0.w;
    xs[4]=v1.x; xs[5]=v1.y; xs[6]=v1.z;  xs[7]=v1.w;
    xs[8]=v2.x; xs[9]=v2.y; xs[10]=v2.z; xs[11]=v2.w;
  }
  float cp = c;
  #pragma unroll
  for (int off=32; off>=1; off>>=1){
    #pragma unroll
    for (int t=0;t<TT;t++) xs[t] += __shfl_xor(xs[t], off, 64);
    cp += __shfl_xor(cp, off, 64);
  }
  if (lane==0){
    #pragma unroll
    for (int t=0;t<TT;t++) xpart[t][wv] = xs[t];
    cpartS[wv] = cp;
  }
  __syncthreads();
  if (tid < TT){
    float v=0.f;
    #pragma unroll
    for (int w8=0; w8<8; w8++) v += xpart[tid][w8];
    st_slot(&xs_slot[tid*NBLK + row], pack_slot(1u, v));
  } else if (tid == TT){
    float v=0.f;
    #pragma unroll
    for (int w8=0; w8<8; w8++) v += cpartS[w8];
    st_slot(&cs_slot[row], pack_slot(1u, v));      // parity 0, tag 1
  }

  // ---- per-wave head + pipelined w1/w2 prefetch registers ----
  const int mh = (wv<4) ? (wv+4) : (wv-4);   // waves 0-3: c-heads 4-7; waves 4-7: x-heads 0-3
  float w1p[2][16];
  float w2p[2];

  if (wv < 4){
    // prefetch c-head weights for s=0
    const float* w1m = w1g + ((0*8+mh)*CC + jbase)*CC + i0;
    #pragma unroll
    for (int jj=0;jj<16;jj++) w1p[0][jj] = w1m[jj*CC];
    w2p[0] = w2g[((0*8+mh)*CC + i0)*CC + ch];
  } else {
    // compute ovx[0] now; prefetch x-head weights for s=1 (used in step-0 body)
    const float* w1m = w1g + ((0*8+mh)*CC + jbase)*CC + i0;
    #pragma unroll
    for (int jj=0;jj<16;jj++) w1p[0][jj] = w1m[jj*CC];
    w2p[0] = w2g[((0*8+mh)*CC + i0)*CC + ch];
    float zx = poll_slot(&xs_slot[0*NBLK + b*CC + i0], 1u);
    float ovn = head_out(zx, w1p[0], w2p[0], jbase);
    if (lane==0) ovxL[0][wv-4] = ovn;
    const float* w1m1 = w1g + ((1*8+mh)*CC + jbase)*CC + i0;
    #pragma unroll
    for (int jj=0;jj<16;jj++) w1p[1][jj] = w1m1[jj*CC];
    w2p[1] = w2g[((1*8+mh)*CC + i0)*CC + ch];
  }
  __syncthreads();

  // ---- 12 sequential steps (fully unrolled) ----
  float hm[TT];
  #pragma unroll
  for (int s=0;s<TT;s++){
    if (wv < 4){
      // c-head: poll this step's csum, compute gate pre-activation
      float zs = poll_slot(&cs_slot[(s&1)*NBLK + b*CC + i0], (unsigned)(s+1));
      float ovc = head_out(zs, w1p[s&1], w2p[s&1], jbase);
      if (lane==0) preS[s&1][wv] = ovxL[s][wv] + ovc;
      if (s < TT-1){
        const float* w1m = w1g + (((s+1)*8+mh)*CC + jbase)*CC + i0;
        #pragma unroll
        for (int jj=0;jj<16;jj++) w1p[(s+1)&1][jj] = w1m[jj*CC];
        w2p[(s+1)&1] = w2g[(((s+1)*8+mh)*CC + i0)*CC + ch];
      }
    } else {
      // x-head: compute ovx[s+1] one step ahead (hop wait of waves 0-3 covers this)
      if (s < TT-1){
        float zx = poll_slot(&xs_slot[(s+1)*NBLK + b*CC + i0], 1u);
        float ovn = head_out(zx, w1p[(s+1)&1], w2p[(s+1)&1], jbase);
        if (lane==0) ovxL[s+1][wv-4] = ovn;
        if (s < TT-2){
          const float* w1m = w1g + (((s+2)*8+mh)*CC + jbase)*CC + i0;
          #pragma unroll
          for (int jj=0;jj<16;jj++) w1p[s&1][jj] = w1m[jj*CC];
          w2p[s&1] = w2g[(((s+2)*8+mh)*CC + i0)*CC + ch];
        }
      }
    }
    __syncthreads();
    const float g0 = preS[s&1][0], g1 = preS[s&1][1];
    const float g2 = preS[s&1][2], g3 = preS[s&1][3];

    float ig = sigmf(g0 + bias0[s]);
    float fg = sigmf(g1 + bias1[s]);
    float ct = tanhff(g3 + bias3[s]);
    c = fg*c + ig*ct;

    if (s < TT-1){
      float csp = c;
      #pragma unroll
      for (int off=32; off>=1; off>>=1) csp += __shfl_xor(csp, off, 64);
      if (lane==0) redS[wv] = csp;
    }
    __syncthreads();
    if (s < TT-1 && tid==0){
      float tot = redS[0]+redS[1]+redS[2]+redS[3]+redS[4]+redS[5]+redS[6]+redS[7];
      st_slot(&cs_slot[((s+1)&1)*NBLK + row], pack_slot((unsigned)(s+2), tot));
    }
    hm[s] = sigmf(g2 + bias2[s]) * tanhff(c);
  }

  // ---- coalesced epilogue ----
  float4* op = (float4*)(outg + (row*NN + n0)*TT);
  op[0] = make_float4(hm[0], hm[1], hm[2],  hm[3]);
  op[1] = make_float4(hm[4], hm[5], hm[6],  hm[7]);
  op[2] = make_float4(hm[8], hm[9], hm[10], hm[11]);
  outg[NBLK*NN*TT + row*NN + n0] = c;
}

extern "C" void kernel_launch(void* const* d_in, const int* in_sizes, int n_in,
                              void* d_out, int out_size, void* d_ws, size_t ws_size,
                              hipStream_t stream)
{
  (void)in_sizes; (void)n_in; (void)out_size; (void)ws_size;
  // setup_inputs order: input, cell, adj, w1, a1, w2, a2, bias
  const float* xg    = (const float*)d_in[0];
  const float* cellg = (const float*)d_in[1];
  const float* w1g   = (const float*)d_in[3];
  const float* w2g   = (const float*)d_in[5];
  const float* biasg = (const float*)d_in[7];
  float* outg = (float*)d_out;
  u64* slots = (u64*)d_ws;

  // reset sync tags every launch (ws is not re-poisoned between replays)
  hipMemsetAsync(d_ws, 0, (size_t)(2*NBLK + TT*NBLK)*sizeof(u64), stream);
  glstm_fused<<<dim3(NBLK), dim3(NTHR), 0, stream>>>(xg, cellg, w1g, w2g, biasg, outg, slots);
}

// Round 4
// 87.819 us; speedup vs baseline: 1.2675x; 1.0219x over previous
//
#include <hip/hip_runtime.h>

typedef unsigned long long u64;

#define CC 32
#define NN 512
#define TT 12
#define NBLK 256     // one block per (batch, channel); == CU count
#define NTHR 512     // one n-element per thread

__device__ __forceinline__ float eluf(float x){ return x>0.f ? x : (__expf(x)-1.f); }
__device__ __forceinline__ float elu3f(float x){ return eluf(eluf(eluf(x))); }
__device__ __forceinline__ float sigmf(float x){
  if (x>=0.f) return 1.f/(1.f+__expf(-x));
  float e=__expf(x); return e/(1.f+e);
}
__device__ __forceinline__ float tanhff(float x){
  return 1.f - 2.f/(__expf(2.f*x)+1.f);
}
__device__ __forceinline__ u64 pack_slot(unsigned tag, float v){
  return ((u64)tag<<32) | (u64)__float_as_uint(v);
}
__device__ __forceinline__ u64 ld_slot(u64* p){
  return __hip_atomic_load(p, __ATOMIC_RELAXED, __HIP_MEMORY_SCOPE_AGENT);
}
__device__ __forceinline__ void st_slot(u64* p, u64 v){
  __hip_atomic_store(p, v, __ATOMIC_RELAXED, __HIP_MEMORY_SCOPE_AGENT);
}
__device__ __forceinline__ float poll_slot(u64* p, unsigned want){
  u64 v = ld_slot(p);
  int guard = 0;
  while ((unsigned)(v>>32) != want){
    __builtin_amdgcn_s_sleep(1);
    v = ld_slot(p);
    if (++guard > 1000000) break;   // terminates instead of hanging
  }
  return __uint_as_float((unsigned)v);
}

// One GAT head output for output-channel ch. zs: lane i0 holds rowsum[i0]
// (duplicated across lane halves). Returns elu^3(N * (elu^2(zs @ w1)) . w2[:,ch])
// on all 64 lanes. w1r[jj] = w1[jbase+jj][i0]; w2r = w2[i0][ch].
__device__ __forceinline__ float head_out(float zs, const float* w1r, float w2r, int jbase){
  float pa = 0.f, pb = 0.f;
  #pragma unroll
  for (int jj=0; jj<8; jj++){
    pa = fmaf(__shfl(zs, jbase+jj,   32), w1r[jj],   pa);
    pb = fmaf(__shfl(zs, jbase+8+jj, 32), w1r[8+jj], pb);
  }
  float part = pa + pb;
  float s1 = part + __shfl_xor(part, 32, 64);     // full 32-dot on both halves
  float h1 = eluf(eluf(s1));
  float pp = h1 * w2r;
  #pragma unroll
  for (int off=16; off>=1; off>>=1) pp += __shfl_xor(pp, off, 32);
  return elu3f(512.f*pp);
}

__device__ __forceinline__ void load_w(const float* __restrict__ w1g,
                                       const float* __restrict__ w2g,
                                       int t, int mh, int i0, int jbase, int ch,
                                       float* w1r, float& w2r){
  const float* w1m = w1g + ((t*8+mh)*CC + jbase)*CC + i0;
  #pragma unroll
  for (int jj=0;jj<16;jj++) w1r[jj] = w1m[jj*CC];
  w2r = w2g[((t*8+mh)*CC + i0)*CC + ch];
}

__global__ __launch_bounds__(NTHR, 1)
void glstm_fused(const float* __restrict__ xg,     // (B,C,N,T)
                 const float* __restrict__ cellg,  // (B,C,N)
                 const float* __restrict__ w1g,    // (T,8,C,C)
                 const float* __restrict__ w2g,    // (T,8,C,C)
                 const float* __restrict__ biasg,  // (4,C,N,T)
                 float* __restrict__ outg,         // (B,C,N,T) ++ (B,C,N)
                 u64* slots)
{
  // 84KB pad: forces 1 block/CU (2 blocks would need >160KB). Volatile-touched
  // below so the allocation isn't eliminated. Restores round-1's residency
  // guarantee that makes the 256-block spin pipeline deterministic.
  __shared__ float pad[21504];
  __shared__ float xpart[TT][8];
  __shared__ float cpartS[8];
  __shared__ float ovxL[TT][4];      // x-head outputs, filled 1 step ahead
  __shared__ float preS[2][4];       // gate pre-activations, parity-buffered
  __shared__ float redSP[2][8];      // csum wave-partials, parity-buffered
  __shared__ unsigned cntS[2];       // arrival counters

  const int blk  = blockIdx.x;
  const int b    = blk & 7;          // batch groups XCD-local under round-robin
  const int ch   = blk >> 3;
  const int row  = b*CC + ch;
  const int tid  = threadIdx.x;
  const int lane = tid & 63;
  const int wv   = tid >> 6;         // 0..7
  const int i0   = lane & 31;
  const int jbase = (lane >> 5) << 4;

  if (tid == 0){
    ((volatile float*)pad)[0] = 0.f;
    cntS[0] = 0u; cntS[1] = 0u;
  }

  u64* cs_slot = slots;              // [2][NBLK] tagged csum, parity-buffered
  u64* xs_slot = slots + 2*NBLK;     // [TT][NBLK] tagged xsum, tag=1

  // ---- per-thread state ----
  const int n0 = tid;
  float c = cellg[row*NN + n0];

  float bias0[TT], bias1[TT], bias2[TT], bias3[TT];
  #pragma unroll
  for (int k=0;k<4;k++){
    const float4* p = (const float4*)(biasg + ((k*CC+ch)*NN + n0)*TT);
    float4 v0=p[0], v1=p[1], v2=p[2];
    float* dst = (k==0)?bias0:(k==1)?bias1:(k==2)?bias2:bias3;
    dst[0]=v0.x; dst[1]=v0.y; dst[2]=v0.z;  dst[3]=v0.w;
    dst[4]=v1.x; dst[5]=v1.y; dst[6]=v1.z;  dst[7]=v1.w;
    dst[8]=v2.x; dst[9]=v2.y; dst[10]=v2.z; dst[11]=v2.w;
  }

  // ---- prologue: xsum per t + csum(state0) ----
  float xs[TT];
  {
    const float4* p = (const float4*)(xg + (row*NN + n0)*TT);
    float4 v0=p[0], v1=p[1], v2=p[2];
    xs[0]=v0.x; xs[1]=v0.y; xs[2]=v0.z;  xs[3]=v0.w;
    xs[4]=v1.x; xs[5]=v1.y; xs[6]=v1.z;  xs[7]=v1.w;
    xs[8]=v2.x; xs[9]=v2.y; xs[10]=v2.z; xs[11]=v2.w;
  }
  float cp = c;
  #pragma unroll
  for (int off=32; off>=1; off>>=1){
    #pragma unroll
    for (int t=0;t<TT;t++) xs[t] += __shfl_xor(xs[t], off, 64);
    cp += __shfl_xor(cp, off, 64);
  }
  if (lane==0){
    #pragma unroll
    for (int t=0;t<TT;t++) xpart[t][wv] = xs[t];
    cpartS[wv] = cp;
  }
  __syncthreads();
  if (tid < TT){
    float v=0.f;
    #pragma unroll
    for (int w8=0; w8<8; w8++) v += xpart[tid][w8];
    st_slot(&xs_slot[tid*NBLK + row], pack_slot(1u, v));
  } else if (tid == TT){
    float v=0.f;
    #pragma unroll
    for (int w8=0; w8<8; w8++) v += cpartS[w8];
    st_slot(&cs_slot[row], pack_slot(1u, v));      // parity 0, tag 1
  }

  // ---- per-wave head, x-sums cached in regs, pipelined weight prefetch ----
  const int mh = (wv<4) ? (wv+4) : (wv-4);   // waves 0-3: c-heads 4-7; 4-7: x-heads 0-3
  float w1p[2][16];
  float w2p[2];
  float zxr[TT];

  if (wv < 4){
    load_w(w1g, w2g, 0, mh, i0, jbase, ch, w1p[0], w2p[0]);
  } else {
    // gather ALL 12 xsums once -> no fabric reads for x-heads inside the loop
    #pragma unroll
    for (int t=0;t<TT;t++)
      zxr[t] = poll_slot(&xs_slot[t*NBLK + b*CC + i0], 1u);
    load_w(w1g, w2g, 0, mh, i0, jbase, ch, w1p[0], w2p[0]);
    float ov0 = head_out(zxr[0], w1p[0], w2p[0], jbase);
    if (lane==0) ovxL[0][wv-4] = ov0;
    load_w(w1g, w2g, 1, mh, i0, jbase, ch, w1p[1], w2p[1]);
  }
  __syncthreads();

  // ---- 12 sequential steps, fully unrolled, ONE barrier per step ----
  float hm[TT];
  #pragma unroll
  for (int s=0;s<TT;s++){
    if (wv < 4){
      // c-head: poll this step's csum (the cross-block hop), compute gate pre-act
      float zs = poll_slot(&cs_slot[(s&1)*NBLK + b*CC + i0], (unsigned)(s+1));
      float ovc = head_out(zs, w1p[s&1], w2p[s&1], jbase);
      if (lane==0) preS[s&1][wv] = ovxL[s][wv] + ovc;
      if (s < TT-1)
        load_w(w1g, w2g, s+1, mh, i0, jbase, ch, w1p[(s+1)&1], w2p[(s+1)&1]);
    } else {
      // x-head: compute ovx[s+1] one step ahead, entirely from registers
      if (s < TT-1){
        float ovn = head_out(zxr[s+1], w1p[(s+1)&1], w2p[(s+1)&1], jbase);
        if (lane==0) ovxL[s+1][wv-4] = ovn;
        if (s < TT-2)
          load_w(w1g, w2g, s+2, mh, i0, jbase, ch, w1p[s&1], w2p[s&1]);
      }
    }
    __syncthreads();
    const float g0 = preS[s&1][0], g1 = preS[s&1][1];
    const float g2 = preS[s&1][2], g3 = preS[s&1][3];

    float ig = sigmf(g0 + bias0[s]);
    float fg = sigmf(g1 + bias1[s]);
    float ct = tanhff(g3 + bias3[s]);
    c = fg*c + ig*ct;

    if (s < TT-1){
      // barrier-free csum publish: per-wave partial + LDS arrival counter;
      // 8th arriver sums in FIXED order (deterministic) and publishes.
      float csp = c;
      #pragma unroll
      for (int off=32; off>=1; off>>=1) csp += __shfl_xor(csp, off, 64);
      if (lane==0){
        const int par = (s+1)&1;
        redSP[par][wv] = csp;                       // LDS write...
        unsigned old = atomicAdd(&cntS[par], 1u);   // ...ordered before cnt (same wave)
        if (old == 7u){
          volatile float* rp = &redSP[par][0];      // volatile: no hoist above atomic
          float tot = rp[0]+rp[1]+rp[2]+rp[3]+rp[4]+rp[5]+rp[6]+rp[7];
          st_slot(&cs_slot[par*NBLK + row], pack_slot((unsigned)(s+2), tot));
          cntS[par] = 0u;                           // next reuse is s+2, barrier-gated
        }
      }
    }
    hm[s] = sigmf(g2 + bias2[s]) * tanhff(c);
  }

  // ---- coalesced epilogue ----
  float4* op = (float4*)(outg + (row*NN + n0)*TT);
  op[0] = make_float4(hm[0], hm[1], hm[2],  hm[3]);
  op[1] = make_float4(hm[4], hm[5], hm[6],  hm[7]);
  op[2] = make_float4(hm[8], hm[9], hm[10], hm[11]);
  outg[NBLK*NN*TT + row*NN + n0] = c;
}

extern "C" void kernel_launch(void* const* d_in, const int* in_sizes, int n_in,
                              void* d_out, int out_size, void* d_ws, size_t ws_size,
                              hipStream_t stream)
{
  (void)in_sizes; (void)n_in; (void)out_size; (void)ws_size;
  // setup_inputs order: input, cell, adj, w1, a1, w2, a2, bias
  const float* xg    = (const float*)d_in[0];
  const float* cellg = (const float*)d_in[1];
  const float* w1g   = (const float*)d_in[3];
  const float* w2g   = (const float*)d_in[5];
  const float* biasg = (const float*)d_in[7];
  float* outg = (float*)d_out;
  u64* slots = (u64*)d_ws;

  // reset sync tags every launch (ws is not re-poisoned between replays)
  hipMemsetAsync(d_ws, 0, (size_t)(2*NBLK + TT*NBLK)*sizeof(u64), stream);
  glstm_fused<<<dim3(NBLK), dim3(NTHR), 0, stream>>>(xg, cellg, w1g, w2g, biasg, outg, slots);
}

// Round 5
// 64.234 us; speedup vs baseline: 1.7328x; 1.3672x over previous
//
#include <hip/hip_runtime.h>

typedef unsigned long long u64;

#define CC 32
#define NN 512
#define TT 12
#define NBLK 256     // one block per (batch, channel); == CU count
#define NTHR 256     // r1-proven shape: 2 n-elements per thread

__device__ __forceinline__ float eluf(float x){ return x>0.f ? x : (__expf(x)-1.f); }
__device__ __forceinline__ float elu3f(float x){ return eluf(eluf(eluf(x))); }
__device__ __forceinline__ float sigmf(float x){
  if (x>=0.f) return 1.f/(1.f+__expf(-x));
  float e=__expf(x); return e/(1.f+e);
}
__device__ __forceinline__ float tanhff(float x){
  return 1.f - 2.f/(__expf(2.f*x)+1.f);   // exact at +/-sat
}
__device__ __forceinline__ u64 pack_slot(unsigned tag, float v){
  return ((u64)tag<<32) | (u64)__float_as_uint(v);
}
__device__ __forceinline__ u64 ld_slot(u64* p){
  return __hip_atomic_load(p, __ATOMIC_RELAXED, __HIP_MEMORY_SCOPE_AGENT);
}
// Publish via atomic RMW: executes at the coherence point -> immediate
// agent-wide visibility (vs plain store that may linger before write-through).
__device__ __forceinline__ void xch_slot(u64* p, u64 v){
  (void)__hip_atomic_exchange(p, v, __ATOMIC_RELAXED, __HIP_MEMORY_SCOPE_AGENT);
}
__device__ __forceinline__ float poll_slot(u64* p, unsigned want){
  u64 v = ld_slot(p);
  int guard = 0;
  while ((unsigned)(v>>32) != want){
    __builtin_amdgcn_s_sleep(1);
    v = ld_slot(p);
    if (++guard > 1000000) break;   // terminates instead of hanging
  }
  return __uint_as_float((unsigned)v);
}

__global__ __launch_bounds__(NTHR, 1)
void glstm_fused(const float* __restrict__ xg,     // (B,C,N,T)
                 const float* __restrict__ cellg,  // (B,C,N)
                 const float* __restrict__ w1g,    // (T,8,C,C)
                 const float* __restrict__ w2g,    // (T,8,C,C)
                 const float* __restrict__ biasg,  // (4,C,N,T)
                 float* __restrict__ outg,         // (B,C,N,T) ++ (B,C,N)
                 u64* slots)
{
  // 96KB bias tile -> 1 block/CU (r1-proven residency for the spin pipeline)
  __shared__ float biasL[4][TT][NN];
  __shared__ float xsL[TT][CC];      // peer xsums, gathered once by wave 0
  __shared__ float csL[CC];          // this step's peer csums (wave-0 polled)
  __shared__ float preS[2][4];       // gate pre-activations, parity-buffered
  __shared__ float redS[4];
  __shared__ float xpart[TT][4];
  __shared__ float cpartS[4];

  const int blk  = blockIdx.x;
  const int b    = blk & 7;          // batch groups XCD-local under round-robin
  const int ch   = blk >> 3;
  const int row  = b*CC + ch;
  const int tid  = threadIdx.x;
  const int lane = tid & 63;
  const int wv   = tid >> 6;         // 0..3
  const int i0   = lane & 31;

  u64* cs_slot = slots;              // [2][NBLK] tagged csum, parity-buffered
  u64* xs_slot = slots + 2*NBLK;     // [TT][NBLK] tagged xsum, tag=1

  // ---- per-thread state: 2 n-elements ----
  const int n0 = 2*tid;
  float2 cc2 = *(const float2*)(cellg + row*NN + n0);
  float c0 = cc2.x, c1 = cc2.y;

  // ---- bias -> LDS (r1-verbatim) ----
  #pragma unroll
  for (int k=0;k<4;k++){
    #pragma unroll
    for (int half=0; half<2; half++){
      int n = tid + half*256;
      const float4* p = (const float4*)(biasg + ((k*CC + ch)*NN + n)*TT);
      float4 v0=p[0], v1=p[1], v2=p[2];
      biasL[k][0][n]=v0.x;  biasL[k][1][n]=v0.y;  biasL[k][2][n]=v0.z;  biasL[k][3][n]=v0.w;
      biasL[k][4][n]=v1.x;  biasL[k][5][n]=v1.y;  biasL[k][6][n]=v1.z;  biasL[k][7][n]=v1.w;
      biasL[k][8][n]=v2.x;  biasL[k][9][n]=v2.y;  biasL[k][10][n]=v2.z; biasL[k][11][n]=v2.w;
    }
  }

  // ---- x rowsums per t + csum(state0) (r1-verbatim reduce) ----
  float xs[TT];
  #pragma unroll
  for (int t=0;t<TT;t++) xs[t]=0.f;
  const float* xrow = xg + row*NN*TT;
  #pragma unroll
  for (int half=0; half<2; half++){
    int n = tid + half*256;
    const float4* p = (const float4*)(xrow + n*TT);
    float4 v0=p[0], v1=p[1], v2=p[2];
    xs[0]+=v0.x;  xs[1]+=v0.y;  xs[2]+=v0.z;  xs[3]+=v0.w;
    xs[4]+=v1.x;  xs[5]+=v1.y;  xs[6]+=v1.z;  xs[7]+=v1.w;
    xs[8]+=v2.x;  xs[9]+=v2.y;  xs[10]+=v2.z; xs[11]+=v2.w;
  }
  float cp = c0 + c1;
  #pragma unroll
  for (int off=32; off>=1; off>>=1){
    #pragma unroll
    for (int t=0;t<TT;t++) xs[t] += __shfl_xor(xs[t], off, 64);
    cp += __shfl_xor(cp, off, 64);
  }
  if (lane == 0){
    #pragma unroll
    for (int t=0;t<TT;t++) xpart[t][wv] = xs[t];
    cpartS[wv] = cp;
  }
  __syncthreads();

  if (tid < TT){
    float v = xpart[tid][0]+xpart[tid][1]+xpart[tid][2]+xpart[tid][3];
    xch_slot(&xs_slot[tid*NBLK + row], pack_slot(1u, v));
  } else if (tid == TT){
    float v = cpartS[0]+cpartS[1]+cpartS[2]+cpartS[3];
    xch_slot(&cs_slot[row], pack_slot(1u, v));     // parity 0, tag 1
  }

  // ---- weight prefetch (double-buffered): head m = wv (x) / wv+4 (c) ----
  const int m = wv + ((lane >> 5) << 2);
  float w1p[2][32];
  float w2p[2];
  {
    const float* w1m = w1g + m*CC*CC + i0;          // t=0
    #pragma unroll
    for (int j=0;j<32;j++) w1p[0][j] = w1m[j*CC];
    w2p[0] = w2g[(m*CC + i0)*CC + ch];
  }

  // ---- wave 0 gathers ALL peer xsums once -> LDS (single poller) ----
  if (wv == 0){
    #pragma unroll
    for (int t=0;t<TT;t++){
      float v = poll_slot(&xs_slot[t*NBLK + b*CC + i0], 1u);
      if (lane < 32) xsL[t][i0] = v;
    }
  }
  __syncthreads();

  // ---- 12 sequential steps, fully unrolled ----
  float hm0[TT], hm1[TT];
  #pragma unroll
  for (int s=0;s<TT;s++){
    // single-poller csum hop: wave 0 only (32 pollers per batch, not 128)
    if (wv == 0){
      float pc = poll_slot(&cs_slot[(s&1)*NBLK + b*CC + i0], (unsigned)(s+1));
      if (lane < 32) csL[i0] = pc;
    }
    __syncthreads();   // B0: csL ready

    // head compute: lower half = x-head (xsL), upper half = c-head (csL)
    float zs = (lane < 32) ? xsL[s][i0] : csL[i0];
    float pa = 0.f, pb = 0.f;
    #pragma unroll
    for (int j=0;j<16;j++){
      pa = fmaf(__shfl(zs, j,    32), w1p[s&1][j],    pa);
      pb = fmaf(__shfl(zs, j+16, 32), w1p[s&1][j+16], pb);
    }
    float s1 = pa + pb;
    float h1 = eluf(eluf(s1));
    float pp = h1 * w2p[s&1];
    #pragma unroll
    for (int off=16; off>=1; off>>=1) pp += __shfl_xor(pp, off, 32);
    float ov = elu3f(512.f*pp);
    float prew = ov + __shfl_xor(ov, 32, 64);      // x-head + c-head
    if (lane == 0) preS[s&1][wv] = prew;

    // prefetch next step's weights (overlaps barrier + gate phase + next hop)
    if (s < TT-1){
      const float* w1m = w1g + ((s+1)*8 + m)*CC*CC + i0;
      #pragma unroll
      for (int j=0;j<32;j++) w1p[(s+1)&1][j] = w1m[j*CC];
      w2p[(s+1)&1] = w2g[(((s+1)*8 + m)*CC + i0)*CC + ch];
    }
    __syncthreads();   // B1: preS ready
    const float g0 = preS[s&1][0], g1 = preS[s&1][1];
    const float g2 = preS[s&1][2], g3 = preS[s&1][3];

    float ig0 = sigmf(g0 + biasL[0][s][n0]);
    float fg0 = sigmf(g1 + biasL[1][s][n0]);
    float ct0 = tanhff(g3 + biasL[3][s][n0]);
    float ig1 = sigmf(g0 + biasL[0][s][n0+1]);
    float fg1 = sigmf(g1 + biasL[1][s][n0+1]);
    float ct1 = tanhff(g3 + biasL[3][s][n0+1]);
    c0 = fg0*c0 + ig0*ct0;
    c1 = fg1*c1 + ig1*ct1;

    if (s < TT-1){
      float csp = c0 + c1;
      #pragma unroll
      for (int off=32; off>=1; off>>=1) csp += __shfl_xor(csp, off, 64);
      if (lane == 0) redS[wv] = csp;
      __syncthreads(); // B2: redS ready
      if (tid == 0){
        float tot = redS[0]+redS[1]+redS[2]+redS[3];
        xch_slot(&cs_slot[((s+1)&1)*NBLK + row], pack_slot((unsigned)(s+2), tot));
      }
    }

    hm0[s] = sigmf(g2 + biasL[2][s][n0])   * tanhff(c0);
    hm1[s] = sigmf(g2 + biasL[2][s][n0+1]) * tanhff(c1);
  }

  // ---- coalesced epilogue: 2 n-rows x 12 t = 24 contiguous floats ----
  float4* op = (float4*)(outg + (row*NN + n0)*TT);
  op[0] = make_float4(hm0[0], hm0[1], hm0[2],  hm0[3]);
  op[1] = make_float4(hm0[4], hm0[5], hm0[6],  hm0[7]);
  op[2] = make_float4(hm0[8], hm0[9], hm0[10], hm0[11]);
  op[3] = make_float4(hm1[0], hm1[1], hm1[2],  hm1[3]);
  op[4] = make_float4(hm1[4], hm1[5], hm1[6],  hm1[7]);
  op[5] = make_float4(hm1[8], hm1[9], hm1[10], hm1[11]);
  *(float2*)(outg + NBLK*NN*TT + row*NN + n0) = make_float2(c0, c1);
}

extern "C" void kernel_launch(void* const* d_in, const int* in_sizes, int n_in,
                              void* d_out, int out_size, void* d_ws, size_t ws_size,
                              hipStream_t stream)
{
  (void)in_sizes; (void)n_in; (void)out_size; (void)ws_size;
  // setup_inputs order: input, cell, adj, w1, a1, w2, a2, bias
  const float* xg    = (const float*)d_in[0];
  const float* cellg = (const float*)d_in[1];
  const float* w1g   = (const float*)d_in[3];
  const float* w2g   = (const float*)d_in[5];
  const float* biasg = (const float*)d_in[7];
  float* outg = (float*)d_out;
  u64* slots = (u64*)d_ws;

  // reset sync tags every launch (ws is not re-poisoned between replays)
  hipMemsetAsync(d_ws, 0, (size_t)(2*NBLK + TT*NBLK)*sizeof(u64), stream);
  glstm_fused<<<dim3(NBLK), dim3(NTHR), 0, stream>>>(xg, cellg, w1g, w2g, biasg, outg, slots);
}

// Round 6
// 44.903 us; speedup vs baseline: 2.4788x; 1.4305x over previous
//
#include <hip/hip_runtime.h>

typedef unsigned long long u64;

#define CC 32
#define NN 512
#define TT 12
#define NBLK 256     // one block per (batch, channel); == CU count
#define NTHR 256     // 2 n-elements per thread (r1-proven shape)

__device__ __forceinline__ float eluf(float x){ return x>0.f ? x : (__expf(x)-1.f); }
__device__ __forceinline__ float elu3f(float x){ return eluf(eluf(eluf(x))); }
__device__ __forceinline__ float sigmf(float x){
  if (x>=0.f) return 1.f/(1.f+__expf(-x));
  float e=__expf(x); return e/(1.f+e);
}
__device__ __forceinline__ float tanhff(float x){
  return 1.f - 2.f/(__expf(2.f*x)+1.f);   // exact at saturation
}
__device__ __forceinline__ u64 pack_slot(unsigned tag, float v){
  return ((u64)tag<<32) | (u64)__float_as_uint(v);
}
__device__ __forceinline__ u64 ld_slot(u64* p){
  return __hip_atomic_load(p, __ATOMIC_RELAXED, __HIP_MEMORY_SCOPE_AGENT);
}
__device__ __forceinline__ void st_slot(u64* p, u64 v){
  __hip_atomic_store(p, v, __ATOMIC_RELAXED, __HIP_MEMORY_SCOPE_AGENT);  // r1-proven
}
__device__ __forceinline__ float poll_slot(u64* p, unsigned want){
  u64 v = ld_slot(p);
  int guard = 0;
  while ((unsigned)(v>>32) != want){
    __builtin_amdgcn_s_sleep(1);
    v = ld_slot(p);
    if (++guard > 1000000) break;   // terminates instead of hanging
  }
  return __uint_as_float((unsigned)v);
}

__global__ __launch_bounds__(NTHR, 1)
void glstm_fused(const float* __restrict__ xg,     // (B,C,N,T)
                 const float* __restrict__ cellg,  // (B,C,N)
                 const float* __restrict__ w1g,    // (T,8,C,C)
                 const float* __restrict__ w2g,    // (T,8,C,C)
                 const float* __restrict__ biasg,  // (4,C,N,T)
                 float* __restrict__ outg,         // (B,C,N,T) ++ (B,C,N)
                 u64* slots)
{
  // 96KB bias tile -> 1 block/CU (proven residency for the spin pipeline)
  __shared__ float biasL[4][TT][NN];
  __shared__ float preS[2][4];       // parity-buffered gate pre-activations
  __shared__ float redS[2][4];       // parity-buffered csum wave-partials
  __shared__ float wpart[13][4];

  const int blk  = blockIdx.x;
  const int b    = blk >> 5;         // r1 mapping (XCD-local mapping measurably hurts)
  const int ch   = blk & 31;
  const int row  = blk;
  const int tid  = threadIdx.x;
  const int lane = tid & 63;
  const int wv   = tid >> 6;         // 0..3
  const int i0   = lane & 31;

  u64* cs_slot = slots;              // [2][NBLK] tagged csum, parity-buffered
  u64* xs_slot = slots + 2*NBLK;     // [TT][NBLK] tagged xsum, tag=1

  // ---- per-thread state: 2 n-elements ----
  const int n0 = 2*tid;
  float2 cc2 = *(const float2*)(cellg + row*NN + n0);
  float c0 = cc2.x, c1 = cc2.y;

  // ---- bias -> LDS (r1-verbatim) ----
  #pragma unroll
  for (int k=0;k<4;k++){
    #pragma unroll
    for (int half=0; half<2; half++){
      int n = tid + half*256;
      const float4* p = (const float4*)(biasg + ((k*CC + ch)*NN + n)*TT);
      float4 v0=p[0], v1=p[1], v2=p[2];
      biasL[k][0][n]=v0.x;  biasL[k][1][n]=v0.y;  biasL[k][2][n]=v0.z;  biasL[k][3][n]=v0.w;
      biasL[k][4][n]=v1.x;  biasL[k][5][n]=v1.y;  biasL[k][6][n]=v1.z;  biasL[k][7][n]=v1.w;
      biasL[k][8][n]=v2.x;  biasL[k][9][n]=v2.y;  biasL[k][10][n]=v2.z; biasL[k][11][n]=v2.w;
    }
  }

  // ---- x rowsums per t + csum(state0) ----
  float xs[TT];
  #pragma unroll
  for (int t=0;t<TT;t++) xs[t]=0.f;
  const float* xrow = xg + row*NN*TT;
  #pragma unroll
  for (int half=0; half<2; half++){
    int n = tid + half*256;
    const float4* p = (const float4*)(xrow + n*TT);
    float4 v0=p[0], v1=p[1], v2=p[2];
    xs[0]+=v0.x;  xs[1]+=v0.y;  xs[2]+=v0.z;  xs[3]+=v0.w;
    xs[4]+=v1.x;  xs[5]+=v1.y;  xs[6]+=v1.z;  xs[7]+=v1.w;
    xs[8]+=v2.x;  xs[9]+=v2.y;  xs[10]+=v2.z; xs[11]+=v2.w;
  }
  float cp = c0 + c1;
  #pragma unroll
  for (int off=32; off>=1; off>>=1){
    #pragma unroll
    for (int t=0;t<TT;t++) xs[t] += __shfl_xor(xs[t], off, 64);
    cp += __shfl_xor(cp, off, 64);
  }
  if (lane == 0){
    #pragma unroll
    for (int t=0;t<TT;t++) wpart[t][wv] = xs[t];
    wpart[12][wv] = cp;
  }
  __syncthreads();
  if (tid < 13){
    float v = wpart[tid][0]+wpart[tid][1]+wpart[tid][2]+wpart[tid][3];
    if (tid < TT) st_slot(&xs_slot[tid*NBLK + row], pack_slot(1u, v));
    else          st_slot(&cs_slot[row],            pack_slot(1u, v));  // parity 0
  }

  // ---- head assignment + weight double-buffer (t=0 now) ----
  const int m = wv + ((lane >> 5) << 2);   // lanes<32: x-heads 0-3; lanes>=32: c-heads 4-7
  float w1p[2][32];
  float w2p[2];
  {
    const float* w1m = w1g + m*CC*CC + i0;
    #pragma unroll
    for (int j=0;j<32;j++) w1p[0][j] = w1m[j*CC];
    w2p[0] = w2g[(m*CC + i0)*CC + ch];
  }

  // ---- gather ALL peer xsums to registers once ----
  float zxr[TT];
  #pragma unroll
  for (int t=0;t<TT;t++)
    zxr[t] = poll_slot(&xs_slot[t*NBLK + b*CC + i0], 1u);

  // ---- 12 sequential steps, fully unrolled, 2 barriers/step ----
  float hm0[TT], hm1[TT];
  #pragma unroll
  for (int s=0;s<TT;s++){
    // hop: all lanes poll this step's peer csum (wave exits when all 32 visible)
    float csv = poll_slot(&cs_slot[(s&1)*NBLK + b*CC + i0], (unsigned)(s+1));
    float zs = (lane < 32) ? zxr[s] : csv;

    // head matvec from prefetched registers (no global loads post-poll)
    float pa = 0.f, pb = 0.f;
    #pragma unroll
    for (int j=0;j<16;j++){
      pa = fmaf(__shfl(zs, j,    32), w1p[s&1][j],    pa);
      pb = fmaf(__shfl(zs, j+16, 32), w1p[s&1][j+16], pb);
    }
    float s1 = pa + pb;
    float h1 = eluf(eluf(s1));
    float pp = h1 * w2p[s&1];
    #pragma unroll
    for (int off=16; off>=1; off>>=1) pp += __shfl_xor(pp, off, 32);
    float ov = elu3f(512.f*pp);
    float prew = ov + __shfl_xor(ov, 32, 64);      // x-head + c-head
    if (lane == 0) preS[s&1][wv] = prew;

    // bias -> regs before the barrier (lgkm drained at B1; gate phase = pure VALU)
    float b00 = biasL[0][s][n0], b01 = biasL[0][s][n0+1];
    float b10 = biasL[1][s][n0], b11 = biasL[1][s][n0+1];
    float b20 = biasL[2][s][n0], b21 = biasL[2][s][n0+1];
    float b30 = biasL[3][s][n0], b31 = biasL[3][s][n0+1];

    __syncthreads();   // B1: preS[s&1] ready
    const float g0 = preS[s&1][0], g1 = preS[s&1][1];
    const float g2 = preS[s&1][2], g3 = preS[s&1][3];

    float ig0 = sigmf(g0 + b00);
    float fg0 = sigmf(g1 + b10);
    float ct0 = tanhff(g3 + b30);
    float ig1 = sigmf(g0 + b01);
    float fg1 = sigmf(g1 + b11);
    float ct1 = tanhff(g3 + b31);
    c0 = fg0*c0 + ig0*ct0;
    c1 = fg1*c1 + ig1*ct1;

    if (s < TT-1){
      const int par = (s+1)&1;
      float csp = c0 + c1;
      #pragma unroll
      for (int off=32; off>=1; off>>=1) csp += __shfl_xor(csp, off, 64);
      if (lane == 0) redS[par][wv] = csp;
      __syncthreads(); // B2: redS ready (also fences preS for next parity reuse)
      if (tid == 0){
        float tot = redS[par][0]+redS[par][1]+redS[par][2]+redS[par][3];
        st_slot(&cs_slot[par*NBLK + row], pack_slot((unsigned)(s+2), tot));
      }
      // prefetch next step's weights AFTER the publish point: never delays the
      // hop; the waitcnt for their use lands inside the next poll wait.
      const float* w1m = w1g + ((s+1)*8 + m)*CC*CC + i0;
      #pragma unroll
      for (int j=0;j<32;j++) w1p[par][j] = w1m[j*CC];
      w2p[par] = w2g[(((s+1)*8 + m)*CC + i0)*CC + ch];
    }

    hm0[s] = sigmf(g2 + b20) * tanhff(c0);
    hm1[s] = sigmf(g2 + b21) * tanhff(c1);
  }

  // ---- coalesced epilogue: 2 n-rows x 12 t contiguous ----
  float4* op = (float4*)(outg + (row*NN + n0)*TT);
  op[0] = make_float4(hm0[0], hm0[1], hm0[2],  hm0[3]);
  op[1] = make_float4(hm0[4], hm0[5], hm0[6],  hm0[7]);
  op[2] = make_float4(hm0[8], hm0[9], hm0[10], hm0[11]);
  op[3] = make_float4(hm1[0], hm1[1], hm1[2],  hm1[3]);
  op[4] = make_float4(hm1[4], hm1[5], hm1[6],  hm1[7]);
  op[5] = make_float4(hm1[8], hm1[9], hm1[10], hm1[11]);
  *(float2*)(outg + NBLK*NN*TT + row*NN + n0) = make_float2(c0, c1);
}

extern "C" void kernel_launch(void* const* d_in, const int* in_sizes, int n_in,
                              void* d_out, int out_size, void* d_ws, size_t ws_size,
                              hipStream_t stream)
{
  (void)in_sizes; (void)n_in; (void)out_size; (void)ws_size;
  // setup_inputs order: input, cell, adj, w1, a1, w2, a2, bias
  const float* xg    = (const float*)d_in[0];
  const float* cellg = (const float*)d_in[1];
  const float* w1g   = (const float*)d_in[3];
  const float* w2g   = (const float*)d_in[5];
  const float* biasg = (const float*)d_in[7];
  float* outg = (float*)d_out;
  u64* slots = (u64*)d_ws;

  // reset sync tags every launch (ws is not re-poisoned between replays)
  hipMemsetAsync(d_ws, 0, (size_t)(2*NBLK + TT*NBLK)*sizeof(u64), stream);
  glstm_fused<<<dim3(NBLK), dim3(NTHR), 0, stream>>>(xg, cellg, w1g, w2g, biasg, outg, slots);
}